// Round 1
// baseline (428.091 us; speedup 1.0000x reference)
//
#include <hip/hip_runtime.h>
#include <stdint.h>

#define B_ 2
#define N_ 16384
#define P_ 1024
#define C_ 256
#define S_ 64
#define CH_ (C_ + 3)   // 259 output channels

#define INF_BITS 0x7F800000u

__device__ __forceinline__ unsigned long long umin64(unsigned long long a, unsigned long long b) {
    return a < b ? a : b;
}

// Block-wide (256 threads) min of u64 keys. Contains barriers; call from all threads.
__device__ unsigned long long block_min_u64(unsigned long long v, unsigned long long* s_red) {
    int tid = threadIdx.x;
#pragma unroll
    for (int o = 32; o > 0; o >>= 1)
        v = umin64(v, (unsigned long long)__shfl_xor(v, o, 64));
    __syncthreads();                 // protect s_red reuse / make prior shared writes visible
    if ((tid & 63) == 0) s_red[tid >> 6] = v;
    __syncthreads();
    unsigned long long r = s_red[0];
#pragma unroll
    for (int w = 1; w < 4; ++w) r = umin64(r, s_red[w]);
    return r;
}

// ---------------- feature transpose: (B,C,N) -> (B,N,C) ----------------
__global__ __launch_bounds__(256) void transpose_kernel(const float* __restrict__ feat,
                                                        float* __restrict__ featT) {
    // grid: B * (C/64) * (N/64) = 2 * 4 * 256 = 2048 tiles
    int t = blockIdx.x;
    int b = t >> 10;
    int rem = t & 1023;
    int cblk = rem >> 8;   // 0..3
    int nblk = rem & 255;  // 0..255
    __shared__ float tile[64][65];
    int tid = threadIdx.x;
    for (int i = tid; i < 64 * 64; i += 256) {
        int cy = i >> 6, nx = i & 63;
        tile[cy][nx] = feat[((size_t)(b * C_ + cblk * 64 + cy)) * N_ + nblk * 64 + nx];
    }
    __syncthreads();
    for (int i = tid; i < 64 * 64; i += 256) {
        int ny = i >> 6, cx = i & 63;
        featT[((size_t)(b * N_ + nblk * 64 + ny)) * C_ + cblk * 64 + cx] = tile[cx][ny];
    }
}

// ---------------- cylinder query: idx (B,P,64) ----------------
__global__ __launch_bounds__(256) void query_kernel(const float* __restrict__ xyz,
                                                    const float* __restrict__ new_xyz,
                                                    const float* __restrict__ rot,
                                                    int* __restrict__ idx_out) {
    __shared__ uint32_t s_score[N_];            // 64 KB
    __shared__ unsigned long long s_red[4];
    __shared__ unsigned long long s_keys[64];
    __shared__ int s_cnt;

    const int tid = threadIdx.x;
    const int bp = blockIdx.x;   // b*P + p
    const int b = bp >> 10;

    if (tid == 0) s_cnt = 0;

    const float cx = new_xyz[bp * 3 + 0];
    const float cy = new_xyz[bp * 3 + 1];
    const float cz = new_xyz[bp * 3 + 2];
    const float r0 = rot[bp * 9 + 0], r1 = rot[bp * 9 + 1], r2 = rot[bp * 9 + 2];
    const float r3 = rot[bp * 9 + 3], r4 = rot[bp * 9 + 4], r5 = rot[bp * 9 + 5];
    const float r6 = rot[bp * 9 + 6], r7 = rot[bp * 9 + 7], r8 = rot[bp * 9 + 8];

    __syncthreads();  // s_cnt initialized

    unsigned long long fb = ~0ull;
    int nvalid = 0;
    const float* xb = xyz + (size_t)b * N_ * 3;
    for (int n = tid; n < N_; n += 256) {
        float px = xb[n * 3 + 0], py = xb[n * 3 + 1], pz = xb[n * 3 + 2];
        // plain subtraction is exact-op (no contraction risk)
        float dx = px - cx, dy = py - cy, dz = pz - cz;
        // d2 = ((dx*dx + dy*dy) + dz*dz), no FMA to match numpy/XLA
        float d2 = __fadd_rn(__fadd_rn(__fmul_rn(dx, dx), __fmul_rn(dy, dy)), __fmul_rn(dz, dz));
        fb = umin64(fb, ((unsigned long long)__float_as_uint(d2) << 32) | (unsigned)n);
        // dcyl_j = sum_d delta_d * rot[j,d], left-to-right, no FMA
        float xr = __fadd_rn(__fadd_rn(__fmul_rn(dx, r0), __fmul_rn(dy, r1)), __fmul_rn(dz, r2));
        float yr = __fadd_rn(__fadd_rn(__fmul_rn(dx, r3), __fmul_rn(dy, r4)), __fmul_rn(dz, r5));
        float zr = __fadd_rn(__fadd_rn(__fmul_rn(dx, r6), __fmul_rn(dy, r7)), __fmul_rn(dz, r8));
        float rad2 = __fadd_rn(__fmul_rn(yr, yr), __fmul_rn(zr, zr));
        float radial = __fsqrt_rn(fmaxf(rad2, 0.0f));
        uint32_t sb = INF_BITS;
        if (radial <= 0.05f && xr >= -0.02f && xr <= 0.04f) {
            float score = __fadd_rn(radial, __fmul_rn(1e-3f, fabsf(xr)));
            sb = __float_as_uint(score);
            ++nvalid;
        }
        s_score[n] = sb;
    }
    atomicAdd(&s_cnt, nvalid);
    unsigned long long fbmin = block_min_u64(fb, s_red);  // barrier inside publishes s_cnt/s_score
    const int v = s_cnt;
    int* out = idx_out + bp * S_;

    if (v == 0) {
        // no point in cylinder: every slot = argmin d2 (first occurrence)
        if (tid < S_) out[tid] = (int)(unsigned)(fbmin & 0xFFFFFFFFu);
        return;
    }

    if (v <= 64) {
        __syncthreads();            // everyone has read v
        if (tid == 0) s_cnt = 0;    // reuse as compaction counter
        __syncthreads();
        for (int n = tid; n < N_; n += 256) {
            uint32_t sb = s_score[n];
            if (sb != INF_BITS) {
                int pos = atomicAdd(&s_cnt, 1);
                s_keys[pos] = ((unsigned long long)sb << 32) | (unsigned)n;
            }
        }
        __syncthreads();
        // pad with unique huge keys
        if (tid >= v && tid < 64)
            s_keys[tid] = 0xFFFFFFFF00000000ull | (unsigned)(0x10000 + tid);
        __syncthreads();
        // rank sort (keys are unique: idx in low bits)
        unsigned long long key = 0;
        int rank = 0;
        if (tid < 64) {
            key = s_keys[tid];
            for (int o = 0; o < 64; ++o) rank += (s_keys[o] < key) ? 1 : 0;
        }
        __syncthreads();
        if (tid < 64) s_keys[rank] = key;
        __syncthreads();
        // fill remaining slots with smallest-index invalid points (ascending).
        // v <= 63 here when needed>0, so first 128 indices contain >= 64 invalid.
        const int needed = 64 - v;
        if (tid < 64 && needed > 0) {
            bool inv0 = (s_score[tid] == INF_BITS);
            unsigned long long m0 = __ballot(inv0);
            int before0 = __popcll(m0 & ((1ull << tid) - 1ull));
            if (inv0 && before0 < needed) s_keys[v + before0] = (unsigned)tid;
            int c0 = __popcll(m0);
            if (c0 < needed) {
                bool inv1 = (s_score[64 + tid] == INF_BITS);
                unsigned long long m1 = __ballot(inv1);
                int b1 = c0 + __popcll(m1 & ((1ull << tid) - 1ull));
                if (inv1 && b1 < needed) s_keys[v + b1] = (unsigned)(64 + tid);
            }
        }
        __syncthreads();
        if (tid < S_) out[tid] = (int)(unsigned)(s_keys[tid] & 0xFFFFFFFFu);
        return;
    }

    // rare path: v > 64, iterative min-extraction over LDS scores
    for (int s = 0; s < S_; ++s) {
        unsigned long long local = ~0ull;
        for (int n = tid; n < N_; n += 256)
            local = umin64(local, ((unsigned long long)s_score[n] << 32) | (unsigned)n);
        unsigned long long m = block_min_u64(local, s_red);
        int sel = (int)(unsigned)(m & 0xFFFFFFFFu);
        if (tid == 0) {
            out[s] = sel;
            s_score[sel] = 0xFFFFFFFFu;  // exclude from further selection
        }
        __syncthreads();
    }
}

// ---------------- grouping: build (B, 3+C, P, S) output ----------------
__global__ __launch_bounds__(256) void group_kernel(const float* __restrict__ featT,
                                                    const float* __restrict__ features,
                                                    const float* __restrict__ xyz,
                                                    const float* __restrict__ new_xyz,
                                                    const float* __restrict__ rot,
                                                    const int* __restrict__ idx,
                                                    float* __restrict__ out, int useT) {
    __shared__ float tile[C_][65];   // padded: conflict-free in both phases
    __shared__ int s_idx[S_];
    const int tid = threadIdx.x;
    const int bp = blockIdx.x;
    const int b = bp >> 10;
    const int p = bp & 1023;

    if (tid < S_) s_idx[tid] = idx[bp * S_ + tid];
    __syncthreads();

    if (tid < S_) {
        int n = s_idx[tid];
        const float* pt = xyz + ((size_t)b * N_ + n) * 3;
        float dx = pt[0] - new_xyz[bp * 3 + 0];
        float dy = pt[1] - new_xyz[bp * 3 + 1];
        float dz = pt[2] - new_xyz[bp * 3 + 2];
        const float* R = rot + bp * 9;
#pragma unroll
        for (int e = 0; e < 3; ++e) {
            // g_e = ((dx*R[0,e] + dy*R[1,e]) + dz*R[2,e]), no FMA
            float g = __fadd_rn(__fadd_rn(__fmul_rn(dx, R[0 * 3 + e]), __fmul_rn(dy, R[1 * 3 + e])),
                                __fmul_rn(dz, R[2 * 3 + e]));
            out[(((size_t)b * CH_ + e) * P_ + p) * S_ + tid] = g;
        }
    }

    // Phase A: gather feature rows into LDS tile[c][s]
    if (useT) {
        for (int i = tid; i < S_ * C_; i += 256) {
            int s = i >> 8;   // uniform per iteration
            int c = i & 255;  // == tid
            tile[c][s] = featT[((size_t)b * N_ + s_idx[s]) * C_ + c];
        }
    } else {
        for (int i = tid; i < S_ * C_; i += 256) {
            int s = i >> 8;
            int c = i & 255;
            tile[c][s] = features[((size_t)b * C_ + c) * N_ + s_idx[s]];
        }
    }
    __syncthreads();
    // Phase B: coalesced output writes, s contiguous
    for (int i = tid; i < S_ * C_; i += 256) {
        int c = i >> 6;  // 0..255
        int s = i & 63;
        out[(((size_t)b * CH_ + 3 + c) * P_ + p) * S_ + s] = tile[c][s];
    }
}

extern "C" void kernel_launch(void* const* d_in, const int* in_sizes, int n_in,
                              void* d_out, int out_size, void* d_ws, size_t ws_size,
                              hipStream_t stream) {
    const float* xyz = (const float*)d_in[0];       // (B,N,3)
    const float* new_xyz = (const float*)d_in[1];   // (B,P,3)
    const float* rot = (const float*)d_in[2];       // (B,P,3,3)
    const float* features = (const float*)d_in[3];  // (B,C,N)
    float* out = (float*)d_out;

    const size_t featT_bytes = (size_t)B_ * N_ * C_ * sizeof(float);  // 32 MB
    const size_t idx_bytes = (size_t)B_ * P_ * S_ * sizeof(int);      // 512 KB
    const int useT = (ws_size >= featT_bytes + idx_bytes) ? 1 : 0;

    float* featT = (float*)d_ws;
    int* idx = useT ? (int*)((char*)d_ws + featT_bytes) : (int*)d_ws;

    if (useT) {
        transpose_kernel<<<2048, 256, 0, stream>>>(features, featT);
    }
    query_kernel<<<B_ * P_, 256, 0, stream>>>(xyz, new_xyz, rot, idx);
    group_kernel<<<B_ * P_, 256, 0, stream>>>(featT, features, xyz, new_xyz, rot, idx, out, useT);
}

// Round 2
// 118.999 us; speedup vs baseline: 3.5974x; 3.5974x over previous
//
#include <hip/hip_runtime.h>
#include <stdint.h>

#define B_ 2
#define N_ 16384
#define P_ 1024
#define C_ 256
#define S_ 64
#define CH_ (C_ + 3)   // 259 output channels
#define CAP_ 512       // key-buffer capacity for selection

#define INF_BITS 0x7F800000u

__device__ __forceinline__ unsigned long long umin64(unsigned long long a, unsigned long long b) {
    return a < b ? a : b;
}

// Block-wide (256 threads) min of u64 keys. Contains barriers; call from all threads.
__device__ unsigned long long block_min_u64(unsigned long long v, unsigned long long* s_red) {
    int tid = threadIdx.x;
#pragma unroll
    for (int o = 32; o > 0; o >>= 1)
        v = umin64(v, (unsigned long long)__shfl_xor(v, o, 64));
    __syncthreads();                 // protect s_red reuse / make prior shared writes visible
    if ((tid & 63) == 0) s_red[tid >> 6] = v;
    __syncthreads();
    unsigned long long r = s_red[0];
#pragma unroll
    for (int w = 1; w < 4; ++w) r = umin64(r, s_red[w]);
    return r;
}

// ---------------- feature transpose: (B,C,N) -> (B,N,C) ----------------
__global__ __launch_bounds__(256) void transpose_kernel(const float* __restrict__ feat,
                                                        float* __restrict__ featT) {
    int t = blockIdx.x;
    int b = t >> 10;
    int rem = t & 1023;
    int cblk = rem >> 8;   // 0..3
    int nblk = rem & 255;  // 0..255
    __shared__ float tile[64][65];
    int tid = threadIdx.x;
    for (int i = tid; i < 64 * 64; i += 256) {
        int cy = i >> 6, nx = i & 63;
        tile[cy][nx] = feat[((size_t)(b * C_ + cblk * 64 + cy)) * N_ + nblk * 64 + nx];
    }
    __syncthreads();
    for (int i = tid; i < 64 * 64; i += 256) {
        int ny = i >> 6, cx = i & 63;
        featT[((size_t)(b * N_ + nblk * 64 + ny)) * C_ + cblk * 64 + cx] = tile[cx][ny];
    }
}

// ---------------- cylinder query: idx (B,P,64) ----------------
__global__ __launch_bounds__(256) void query_kernel(const float* __restrict__ xyz,
                                                    const float* __restrict__ new_xyz,
                                                    const float* __restrict__ rot,
                                                    int* __restrict__ idx_out) {
    __shared__ uint32_t s_score[N_];              // 64 KB
    __shared__ unsigned long long s_keys[CAP_];   // 4 KB
    __shared__ uint32_t s_hist[256];              // 1 KB
    __shared__ unsigned long long s_red[4];
    __shared__ uint32_t s_wsum[4];
    __shared__ int s_cnt;
    __shared__ int s_sel;
    __shared__ uint32_t s_k;

    const int tid = threadIdx.x;
    const int bp = blockIdx.x;   // b*P + p
    const int b = bp >> 10;

    if (tid == 0) s_cnt = 0;

    const float cx = new_xyz[bp * 3 + 0];
    const float cy = new_xyz[bp * 3 + 1];
    const float cz = new_xyz[bp * 3 + 2];
    const float r0 = rot[bp * 9 + 0], r1 = rot[bp * 9 + 1], r2 = rot[bp * 9 + 2];
    const float r3 = rot[bp * 9 + 3], r4 = rot[bp * 9 + 4], r5 = rot[bp * 9 + 5];
    const float r6 = rot[bp * 9 + 6], r7 = rot[bp * 9 + 7], r8 = rot[bp * 9 + 8];

    __syncthreads();  // s_cnt initialized

    unsigned long long fb = ~0ull;
    int nvalid = 0;
    const float* xb = xyz + (size_t)b * N_ * 3;
#pragma unroll 4
    for (int n = tid; n < N_; n += 256) {
        float px = xb[n * 3 + 0], py = xb[n * 3 + 1], pz = xb[n * 3 + 2];
        float dx = px - cx, dy = py - cy, dz = pz - cz;
        // d2 = ((dx*dx + dy*dy) + dz*dz), no FMA to match numpy/XLA
        float d2 = __fadd_rn(__fadd_rn(__fmul_rn(dx, dx), __fmul_rn(dy, dy)), __fmul_rn(dz, dz));
        fb = umin64(fb, ((unsigned long long)__float_as_uint(d2) << 32) | (unsigned)n);
        // dcyl_j = sum_d delta_d * rot[j,d], left-to-right, no FMA
        float xr = __fadd_rn(__fadd_rn(__fmul_rn(dx, r0), __fmul_rn(dy, r1)), __fmul_rn(dz, r2));
        float yr = __fadd_rn(__fadd_rn(__fmul_rn(dx, r3), __fmul_rn(dy, r4)), __fmul_rn(dz, r5));
        float zr = __fadd_rn(__fadd_rn(__fmul_rn(dx, r6), __fmul_rn(dy, r7)), __fmul_rn(dz, r8));
        float rad2 = __fadd_rn(__fmul_rn(yr, yr), __fmul_rn(zr, zr));
        float radial = __fsqrt_rn(fmaxf(rad2, 0.0f));
        uint32_t sb = INF_BITS;
        if (radial <= 0.05f && xr >= -0.02f && xr <= 0.04f) {
            float score = __fadd_rn(radial, __fmul_rn(1e-3f, fabsf(xr)));
            sb = __float_as_uint(score);
            ++nvalid;
        }
        s_score[n] = sb;
    }
    atomicAdd(&s_cnt, nvalid);
    unsigned long long fbmin = block_min_u64(fb, s_red);  // barriers inside publish s_cnt/s_score
    const int v = s_cnt;
    int* out = idx_out + bp * S_;

    if (v == 0) {
        // no point in cylinder: every slot = argmin d2 (first occurrence)
        if (tid < S_) out[tid] = (int)(unsigned)(fbmin & 0xFFFFFFFFu);
        return;
    }

    if (v <= 64) {
        __syncthreads();            // everyone has read v
        if (tid == 0) s_cnt = 0;    // reuse as compaction counter
        __syncthreads();
        for (int n = tid; n < N_; n += 256) {
            uint32_t sb = s_score[n];
            if (sb != INF_BITS) {
                int pos = atomicAdd(&s_cnt, 1);
                s_keys[pos] = ((unsigned long long)sb << 32) | (unsigned)n;
            }
        }
        __syncthreads();
        // pad with unique huge keys
        if (tid >= v && tid < 64)
            s_keys[tid] = 0xFFFFFFFF00000000ull | (unsigned)(0x10000 + tid);
        __syncthreads();
        // rank sort (keys are unique: idx in low bits)
        unsigned long long key = 0;
        int rank = 0;
        if (tid < 64) {
            key = s_keys[tid];
            for (int o = 0; o < 64; ++o) rank += (s_keys[o] < key) ? 1 : 0;
        }
        __syncthreads();
        if (tid < 64) s_keys[rank] = key;
        __syncthreads();
        // fill remaining slots with smallest-index invalid points (ascending).
        // v <= 63 here when needed>0, so first 128 indices contain >= 64 invalid.
        const int needed = 64 - v;
        if (tid < 64 && needed > 0) {
            bool inv0 = (s_score[tid] == INF_BITS);
            unsigned long long m0 = __ballot(inv0);
            int before0 = __popcll(m0 & ((1ull << tid) - 1ull));
            if (inv0 && before0 < needed) s_keys[v + before0] = (unsigned)tid;
            int c0 = __popcll(m0);
            if (c0 < needed) {
                bool inv1 = (s_score[64 + tid] == INF_BITS);
                unsigned long long m1 = __ballot(inv1);
                int b1 = c0 + __popcll(m1 & ((1ull << tid) - 1ull));
                if (inv1 && b1 < needed) s_keys[v + b1] = (unsigned)(64 + tid);
            }
        }
        __syncthreads();
        if (tid < S_) out[tid] = (int)(unsigned)(s_keys[tid] & 0xFFFFFFFFu);
        return;
    }

    // ---- v > 64: threshold (radix-select if needed) + compact + rank-sort ----
    uint32_t T;
    if (v <= CAP_) {
        T = 0x7F7FFFFFu;  // accept all valid scores (all finite)
    } else {
        // 4-pass 8-bit radix select of the 64th smallest score (with multiplicity)
        uint32_t prefix = 0, mask = 0, kk = 64;
        for (int pass = 0; pass < 4; ++pass) {
            const int shift = 24 - 8 * pass;
            __syncthreads();
            s_hist[tid] = 0;
            __syncthreads();
            for (int n = tid; n < N_; n += 256) {
                uint32_t sb = s_score[n];
                if (sb != INF_BITS && (sb & mask) == prefix)
                    atomicAdd(&s_hist[(sb >> shift) & 255u], 1u);
            }
            __syncthreads();
            uint32_t cnt = s_hist[tid];
            uint32_t x = cnt;
#pragma unroll
            for (int o = 1; o < 64; o <<= 1) {
                uint32_t y = __shfl_up(x, o, 64);
                if ((tid & 63) >= o) x += y;
            }
            if ((tid & 63) == 63) s_wsum[tid >> 6] = x;
            __syncthreads();
            uint32_t woff = 0;
            for (int w = 0; w < (tid >> 6); ++w) woff += s_wsum[w];
            uint32_t incl = x + woff;
            uint32_t excl = incl - cnt;
            if (kk > excl && kk <= incl) {  // exactly one thread
                s_sel = tid;
                s_k = kk - excl;
            }
            __syncthreads();
            prefix |= ((uint32_t)s_sel) << shift;
            mask |= 255u << shift;
            kk = s_k;
        }
        T = prefix;  // exact score value of the 64th smallest
    }

    // compact all keys with score <= T (>= 64 of them; ~64 in radix case)
    __syncthreads();
    if (tid == 0) s_cnt = 0;
    __syncthreads();
    for (int n = tid; n < N_; n += 256) {
        uint32_t sb = s_score[n];
        if (sb != INF_BITS && sb <= T) {
            int pos = atomicAdd(&s_cnt, 1);
            if (pos < CAP_) s_keys[pos] = ((unsigned long long)sb << 32) | (unsigned)n;
        }
    }
    __syncthreads();
    const int c = s_cnt;

    if (c <= CAP_) {
        // rank-sort; only ranks < 64 are emitted
        for (int i = tid; i < c; i += 256) {
            unsigned long long key = s_keys[i];
            int rank = 0;
            for (int j = 0; j < c; ++j) rank += (s_keys[j] < key) ? 1 : 0;
            if (rank < 64) out[rank] = (int)(unsigned)(key & 0xFFFFFFFFu);
        }
        return;
    }

    // overflow fallback (> CAP_ exact-tie keys; practically unreachable):
    // serial min-extraction over LDS scores
    for (int s = 0; s < S_; ++s) {
        unsigned long long local = ~0ull;
        for (int n = tid; n < N_; n += 256)
            local = umin64(local, ((unsigned long long)s_score[n] << 32) | (unsigned)n);
        unsigned long long m = block_min_u64(local, s_red);
        int sel = (int)(unsigned)(m & 0xFFFFFFFFu);
        if (tid == 0) {
            out[s] = sel;
            s_score[sel] = 0xFFFFFFFFu;  // exclude from further selection
        }
        __syncthreads();
    }
}

// ---------------- grouping: build (B, 3+C, P, S) output ----------------
__global__ __launch_bounds__(256) void group_kernel(const float* __restrict__ featT,
                                                    const float* __restrict__ features,
                                                    const float* __restrict__ xyz,
                                                    const float* __restrict__ new_xyz,
                                                    const float* __restrict__ rot,
                                                    const int* __restrict__ idx,
                                                    float* __restrict__ out, int useT) {
    __shared__ float tile[C_][65];   // padded: conflict-free in both phases
    __shared__ int s_idx[S_];
    const int tid = threadIdx.x;
    const int bp = blockIdx.x;
    const int b = bp >> 10;
    const int p = bp & 1023;

    if (tid < S_) s_idx[tid] = idx[bp * S_ + tid];
    __syncthreads();

    if (tid < S_) {
        int n = s_idx[tid];
        const float* pt = xyz + ((size_t)b * N_ + n) * 3;
        float dx = pt[0] - new_xyz[bp * 3 + 0];
        float dy = pt[1] - new_xyz[bp * 3 + 1];
        float dz = pt[2] - new_xyz[bp * 3 + 2];
        const float* R = rot + bp * 9;
#pragma unroll
        for (int e = 0; e < 3; ++e) {
            float g = __fadd_rn(__fadd_rn(__fmul_rn(dx, R[0 * 3 + e]), __fmul_rn(dy, R[1 * 3 + e])),
                                __fmul_rn(dz, R[2 * 3 + e]));
            out[(((size_t)b * CH_ + e) * P_ + p) * S_ + tid] = g;
        }
    }

    // Phase A: gather feature rows into LDS tile[c][s]
    if (useT) {
        for (int i = tid; i < S_ * C_; i += 256) {
            int s = i >> 8;   // uniform per iteration
            int c = i & 255;  // == tid
            tile[c][s] = featT[((size_t)b * N_ + s_idx[s]) * C_ + c];
        }
    } else {
        for (int i = tid; i < S_ * C_; i += 256) {
            int s = i >> 8;
            int c = i & 255;
            tile[c][s] = features[((size_t)b * C_ + c) * N_ + s_idx[s]];
        }
    }
    __syncthreads();
    // Phase B: coalesced output writes, s contiguous
    for (int i = tid; i < S_ * C_; i += 256) {
        int c = i >> 6;  // 0..255
        int s = i & 63;
        out[(((size_t)b * CH_ + 3 + c) * P_ + p) * S_ + s] = tile[c][s];
    }
}

extern "C" void kernel_launch(void* const* d_in, const int* in_sizes, int n_in,
                              void* d_out, int out_size, void* d_ws, size_t ws_size,
                              hipStream_t stream) {
    const float* xyz = (const float*)d_in[0];       // (B,N,3)
    const float* new_xyz = (const float*)d_in[1];   // (B,P,3)
    const float* rot = (const float*)d_in[2];       // (B,P,3,3)
    const float* features = (const float*)d_in[3];  // (B,C,N)
    float* out = (float*)d_out;

    const size_t featT_bytes = (size_t)B_ * N_ * C_ * sizeof(float);  // 32 MB
    const size_t idx_bytes = (size_t)B_ * P_ * S_ * sizeof(int);      // 512 KB
    const int useT = (ws_size >= featT_bytes + idx_bytes) ? 1 : 0;

    float* featT = (float*)d_ws;
    int* idx = useT ? (int*)((char*)d_ws + featT_bytes) : (int*)d_ws;

    if (useT) {
        transpose_kernel<<<2048, 256, 0, stream>>>(features, featT);
    }
    query_kernel<<<B_ * P_, 256, 0, stream>>>(xyz, new_xyz, rot, idx);
    group_kernel<<<B_ * P_, 256, 0, stream>>>(featT, features, xyz, new_xyz, rot, idx, out, useT);
}

// Round 3
// 87.593 us; speedup vs baseline: 4.8873x; 1.3585x over previous
//
#include <hip/hip_runtime.h>
#include <stdint.h>

#define B_ 2
#define N_ 16384
#define P_ 1024
#define C_ 256
#define S_ 64
#define CH_ (C_ + 3)   // 259 output channels
#define CAP_ 512       // key-buffer capacity for selection

#define INF_BITS 0x7F800000u

typedef unsigned long long u64;

__device__ __forceinline__ u64 umin64(u64 a, u64 b) { return a < b ? a : b; }

// Block-wide (256 threads) min of u64 keys. Contains barriers; call from all threads.
__device__ u64 block_min_u64(u64 v, u64* s_red) {
    int tid = threadIdx.x;
#pragma unroll
    for (int o = 32; o > 0; o >>= 1)
        v = umin64(v, (u64)__shfl_xor(v, o, 64));
    __syncthreads();
    if ((tid & 63) == 0) s_red[tid >> 6] = v;
    __syncthreads();
    u64 r = s_red[0];
#pragma unroll
    for (int w = 1; w < 4; ++w) r = umin64(r, s_red[w]);
    return r;
}

// Exact score computation (bit-identical to reference evaluation order; no FMA).
__device__ __forceinline__ uint32_t score_bits(const float* __restrict__ xb, int n,
                                               float cx, float cy, float cz,
                                               float r0, float r1, float r2,
                                               float r3, float r4, float r5,
                                               float r6, float r7, float r8) {
    float px = xb[n * 3 + 0], py = xb[n * 3 + 1], pz = xb[n * 3 + 2];
    float dx = px - cx, dy = py - cy, dz = pz - cz;
    float xr = __fadd_rn(__fadd_rn(__fmul_rn(dx, r0), __fmul_rn(dy, r1)), __fmul_rn(dz, r2));
    float yr = __fadd_rn(__fadd_rn(__fmul_rn(dx, r3), __fmul_rn(dy, r4)), __fmul_rn(dz, r5));
    float zr = __fadd_rn(__fadd_rn(__fmul_rn(dx, r6), __fmul_rn(dy, r7)), __fmul_rn(dz, r8));
    float rad2 = __fadd_rn(__fmul_rn(yr, yr), __fmul_rn(zr, zr));
    float radial = __fsqrt_rn(fmaxf(rad2, 0.0f));
    uint32_t sb = INF_BITS;
    if (radial <= 0.05f && xr >= -0.02f && xr <= 0.04f)
        sb = __float_as_uint(__fadd_rn(radial, __fmul_rn(1e-3f, fabsf(xr))));
    return sb;
}

// ---------------- feature transpose: (B,C,N) -> (B,N,C) ----------------
__global__ __launch_bounds__(256) void transpose_kernel(const float* __restrict__ feat,
                                                        float* __restrict__ featT) {
    int t = blockIdx.x;
    int b = t >> 10;
    int rem = t & 1023;
    int cblk = rem >> 8;   // 0..3
    int nblk = rem & 255;  // 0..255
    __shared__ float tile[64][65];
    int tid = threadIdx.x;
    for (int i = tid; i < 64 * 64; i += 256) {
        int cy = i >> 6, nx = i & 63;
        tile[cy][nx] = feat[((size_t)(b * C_ + cblk * 64 + cy)) * N_ + nblk * 64 + nx];
    }
    __syncthreads();
    for (int i = tid; i < 64 * 64; i += 256) {
        int ny = i >> 6, cx = i & 63;
        featT[((size_t)(b * N_ + nblk * 64 + ny)) * C_ + cblk * 64 + cx] = tile[cx][ny];
    }
}

// ---------------- cylinder query: idx (B,P,64) ----------------
__global__ __launch_bounds__(256) void query_kernel(const float* __restrict__ xyz,
                                                    const float* __restrict__ new_xyz,
                                                    const float* __restrict__ rot,
                                                    int* __restrict__ idx_out) {
    __shared__ u64 s_keys[CAP_];         // 4 KB
    __shared__ uint32_t s_hist[4][256];  // 4 KB (per-wave split: less atomic serialization)
    __shared__ u64 s_red[4];
    __shared__ uint32_t s_wsum[4];
    __shared__ int s_v[128];             // validity of n in [0,128) for the fill step
    __shared__ int s_cnt;
    __shared__ int s_sel;
    __shared__ uint32_t s_k;

    const int tid = threadIdx.x;
    const int lane = tid & 63;
    const int wid = tid >> 6;
    const int bp = blockIdx.x;   // b*P + p
    const int b = bp >> 10;

    if (tid == 0) s_cnt = 0;

    const float cx = new_xyz[bp * 3 + 0];
    const float cy = new_xyz[bp * 3 + 1];
    const float cz = new_xyz[bp * 3 + 2];
    const float r0 = rot[bp * 9 + 0], r1 = rot[bp * 9 + 1], r2 = rot[bp * 9 + 2];
    const float r3 = rot[bp * 9 + 3], r4 = rot[bp * 9 + 4], r5 = rot[bp * 9 + 5];
    const float r6 = rot[bp * 9 + 6], r7 = rot[bp * 9 + 7], r8 = rot[bp * 9 + 8];

    __syncthreads();  // s_cnt initialized

    const float* xb = xyz + (size_t)b * N_ * 3;

    // Main pass: evaluate all N points; wave-aggregated compaction of valid keys.
#pragma unroll 2
    for (int n = tid; n < N_; n += 256) {
        uint32_t sb = score_bits(xb, n, cx, cy, cz, r0, r1, r2, r3, r4, r5, r6, r7, r8);
        bool valid = (sb != INF_BITS);
        if (n < 128) s_v[n] = valid ? 1 : 0;
        u64 msk = __ballot(valid);
        if (msk) {
            int leader = __builtin_ctzll(msk);
            int cnt = __popcll(msk);
            int base = 0;
            if (lane == leader) base = atomicAdd(&s_cnt, cnt);
            base = __shfl(base, leader, 64);
            if (valid) {
                int pos = base + __popcll(msk & ((1ull << lane) - 1ull));
                if (pos < CAP_) s_keys[pos] = ((u64)sb << 32) | (unsigned)n;
            }
        }
    }
    __syncthreads();
    const int v = s_cnt;
    int* out = idx_out + bp * S_;

    if (v == 0) {
        // rare: no point in cylinder -> every slot = argmin d2 (first occurrence)
        u64 fb = ~0ull;
        for (int n = tid; n < N_; n += 256) {
            float px = xb[n * 3 + 0], py = xb[n * 3 + 1], pz = xb[n * 3 + 2];
            float dx = px - cx, dy = py - cy, dz = pz - cz;
            float d2 = __fadd_rn(__fadd_rn(__fmul_rn(dx, dx), __fmul_rn(dy, dy)),
                                 __fmul_rn(dz, dz));
            fb = umin64(fb, ((u64)__float_as_uint(d2) << 32) | (unsigned)n);
        }
        u64 m = block_min_u64(fb, s_red);
        if (tid < S_) out[tid] = (int)(unsigned)(m & 0xFFFFFFFFu);
        return;
    }

    if (v <= 64) {
        // pad to 64 with unique huge keys
        if (tid >= v && tid < 64)
            s_keys[tid] = 0xFFFFFFFF00000000ull | (unsigned)(0x10000 + tid);
        __syncthreads();
        // rank sort (keys unique: idx in low bits)
        u64 key = 0;
        int rank = 0;
        if (tid < 64) {
            key = s_keys[tid];
            for (int o = 0; o < 64; ++o) rank += (s_keys[o] < key) ? 1 : 0;
        }
        __syncthreads();
        if (tid < 64) s_keys[rank] = key;
        __syncthreads();
        // fill remaining slots with smallest-index invalid points (ascending).
        // v <= 63 when needed>0, so n in [0,128) contains >= 65 invalid points.
        const int needed = 64 - v;
        if (tid < 64 && needed > 0) {
            bool inv0 = (s_v[tid] == 0);
            u64 m0 = __ballot(inv0);
            int before0 = __popcll(m0 & ((1ull << tid) - 1ull));
            if (inv0 && before0 < needed) s_keys[v + before0] = (unsigned)tid;
            int c0 = __popcll(m0);
            if (c0 < needed) {
                bool inv1 = (s_v[64 + tid] == 0);
                u64 m1 = __ballot(inv1);
                int b1 = c0 + __popcll(m1 & ((1ull << tid) - 1ull));
                if (inv1 && b1 < needed) s_keys[v + b1] = (unsigned)(64 + tid);
            }
        }
        __syncthreads();
        if (tid < S_) out[tid] = (int)(unsigned)(s_keys[tid] & 0xFFFFFFFFu);
        return;
    }

    if (v <= CAP_) {
        // all valid keys already compacted; rank-sort, emit ranks < 64
        for (int i = tid; i < v; i += 256) {
            u64 key = s_keys[i];
            int rank = 0;
            for (int j = 0; j < v; ++j) rank += (s_keys[j] < key) ? 1 : 0;
            if (rank < 64) out[rank] = (int)(unsigned)(key & 0xFFFFFFFFu);
        }
        return;
    }

    // ---- rare: v > CAP_. 4-pass radix select of 64th-smallest score (recompute). ----
    uint32_t prefix = 0, mask = 0, kk = 64;
    for (int pass = 0; pass < 4; ++pass) {
        const int shift = 24 - 8 * pass;
        __syncthreads();
        s_hist[0][tid] = 0; s_hist[1][tid] = 0; s_hist[2][tid] = 0; s_hist[3][tid] = 0;
        __syncthreads();
        for (int n = tid; n < N_; n += 256) {
            uint32_t sb = score_bits(xb, n, cx, cy, cz, r0, r1, r2, r3, r4, r5, r6, r7, r8);
            if (sb != INF_BITS && (sb & mask) == prefix)
                atomicAdd(&s_hist[wid][(sb >> shift) & 255u], 1u);
        }
        __syncthreads();
        uint32_t cnt = s_hist[0][tid] + s_hist[1][tid] + s_hist[2][tid] + s_hist[3][tid];
        uint32_t x = cnt;
#pragma unroll
        for (int o = 1; o < 64; o <<= 1) {
            uint32_t y = __shfl_up(x, o, 64);
            if ((tid & 63) >= o) x += y;
        }
        if ((tid & 63) == 63) s_wsum[wid] = x;
        __syncthreads();
        uint32_t woff = 0;
        for (int w = 0; w < wid; ++w) woff += s_wsum[w];
        uint32_t incl = x + woff;
        uint32_t excl = incl - cnt;
        if (kk > excl && kk <= incl) {  // exactly one thread
            s_sel = tid;
            s_k = kk - excl;
        }
        __syncthreads();
        prefix |= ((uint32_t)s_sel) << shift;
        mask |= 255u << shift;
        kk = s_k;
    }
    const uint32_t T = prefix;  // exact 64th-smallest score bits

    __syncthreads();
    if (tid == 0) s_cnt = 0;
    __syncthreads();
    for (int n = tid; n < N_; n += 256) {
        uint32_t sb = score_bits(xb, n, cx, cy, cz, r0, r1, r2, r3, r4, r5, r6, r7, r8);
        if (sb != INF_BITS && sb <= T) {
            int pos = atomicAdd(&s_cnt, 1);
            if (pos < CAP_) s_keys[pos] = ((u64)sb << 32) | (unsigned)n;
        }
    }
    __syncthreads();
    int c = s_cnt;
    if (c > CAP_) c = CAP_;  // unreachable without >448 exact float ties
    for (int i = tid; i < c; i += 256) {
        u64 key = s_keys[i];
        int rank = 0;
        for (int j = 0; j < c; ++j) rank += (s_keys[j] < key) ? 1 : 0;
        if (rank < 64) out[rank] = (int)(unsigned)(key & 0xFFFFFFFFu);
    }
}

// ---------------- grouping: build (B, 3+C, P, S) output ----------------
__global__ __launch_bounds__(256) void group_kernel(const float* __restrict__ featT,
                                                    const float* __restrict__ features,
                                                    const float* __restrict__ xyz,
                                                    const float* __restrict__ new_xyz,
                                                    const float* __restrict__ rot,
                                                    const int* __restrict__ idx,
                                                    float* __restrict__ out, int useT) {
    __shared__ float tile[C_][33];   // 33.8 KB: stride 33 (odd) -> conflict-free both phases
    __shared__ int s_idx[S_];
    const int tid = threadIdx.x;
    const int bp = blockIdx.x;
    const int b = bp >> 10;
    const int p = bp & 1023;

    if (tid < S_) s_idx[tid] = idx[bp * S_ + tid];
    __syncthreads();

    if (tid < S_) {
        int n = s_idx[tid];
        const float* pt = xyz + ((size_t)b * N_ + n) * 3;
        float dx = pt[0] - new_xyz[bp * 3 + 0];
        float dy = pt[1] - new_xyz[bp * 3 + 1];
        float dz = pt[2] - new_xyz[bp * 3 + 2];
        const float* R = rot + bp * 9;
#pragma unroll
        for (int e = 0; e < 3; ++e) {
            float g = __fadd_rn(__fadd_rn(__fmul_rn(dx, R[0 * 3 + e]), __fmul_rn(dy, R[1 * 3 + e])),
                                __fmul_rn(dz, R[2 * 3 + e]));
            out[(((size_t)b * CH_ + e) * P_ + p) * S_ + tid] = g;
        }
    }

    // two s-halves of 32 samples each
    for (int h = 0; h < 2; ++h) {
        if (h) __syncthreads();  // protect tile reuse
        // Phase A: gather feature rows into tile[c][sl] (one 1KB row per iteration, coalesced)
        if (useT) {
            for (int i = tid; i < 32 * C_; i += 256) {
                int sl = i >> 8;      // wave-uniform row
                int n = s_idx[h * 32 + sl];
                tile[tid][sl] = featT[((size_t)b * N_ + n) * C_ + tid];
            }
        } else {
            for (int i = tid; i < 32 * C_; i += 256) {
                int sl = i >> 8;
                int n = s_idx[h * 32 + sl];
                tile[tid][sl] = features[((size_t)b * C_ + tid) * N_ + n];
            }
        }
        __syncthreads();
        // Phase B: coalesced output writes, s contiguous (128B per 32-lane group)
        for (int i = tid; i < 32 * C_; i += 256) {
            int c = i >> 5;     // 0..255
            int sl = i & 31;
            out[(((size_t)b * CH_ + 3 + c) * P_ + p) * S_ + h * 32 + sl] = tile[c][sl];
        }
    }
}

extern "C" void kernel_launch(void* const* d_in, const int* in_sizes, int n_in,
                              void* d_out, int out_size, void* d_ws, size_t ws_size,
                              hipStream_t stream) {
    const float* xyz = (const float*)d_in[0];       // (B,N,3)
    const float* new_xyz = (const float*)d_in[1];   // (B,P,3)
    const float* rot = (const float*)d_in[2];       // (B,P,3,3)
    const float* features = (const float*)d_in[3];  // (B,C,N)
    float* out = (float*)d_out;

    const size_t featT_bytes = (size_t)B_ * N_ * C_ * sizeof(float);  // 32 MB
    const size_t idx_bytes = (size_t)B_ * P_ * S_ * sizeof(int);      // 512 KB
    const int useT = (ws_size >= featT_bytes + idx_bytes) ? 1 : 0;

    float* featT = (float*)d_ws;
    int* idx = useT ? (int*)((char*)d_ws + featT_bytes) : (int*)d_ws;

    if (useT) {
        transpose_kernel<<<2048, 256, 0, stream>>>(features, featT);
    }
    query_kernel<<<B_ * P_, 256, 0, stream>>>(xyz, new_xyz, rot, idx);
    group_kernel<<<B_ * P_, 256, 0, stream>>>(featT, features, xyz, new_xyz, rot, idx, out, useT);
}